// Round 6
// baseline (228.769 us; speedup 1.0000x reference)
//
#include <hip/hip_runtime.h>

// out[t][i][j] = sum_k x[i][k]*W[j][k] + bias[j] + sum_r low[t][i][r]*Bm[ti][j][r]
// low[t][i][r] = sum_k x[i][k]*A[ti][r][k]
// Base GEMM via split-bf16 MFMA: x*W ~= xh*Wh + xh*Wl + xl*Wh (fp32 accum).

typedef __attribute__((ext_vector_type(8))) short short8;
typedef __attribute__((ext_vector_type(4))) float f32x4;
typedef __attribute__((ext_vector_type(4))) unsigned short us4;
typedef __attribute__((ext_vector_type(8))) unsigned short us8;

namespace {
constexpr int kM = 16384, kDin = 1024, kDout = 1024, kR = 16, kT = 4;
// d_ws byte offsets
constexpr size_t OFF_XH  = 0;               // [16384][1024] bf16 = 32 MiB
constexpr size_t OFF_XL  = 33554432;        // 32 MiB
constexpr size_t OFF_WH  = 67108864;        // [1024][1024] bf16 = 2 MiB
constexpr size_t OFF_WL  = 69206016;        // 2 MiB
constexpr size_t OFF_LOW = 71303168;        // [4][16384][16] bf16 = 2 MiB
}

__device__ inline unsigned short f2bf(float f) {
  unsigned int u = __float_as_uint(f);
  u += 0x7fff + ((u >> 16) & 1);  // RNE
  return (unsigned short)(u >> 16);
}
__device__ inline float bf2f(unsigned short h) {
  return __uint_as_float(((unsigned int)h) << 16);
}
__device__ inline void gload_lds16(const void* g, void* l) {
  __builtin_amdgcn_global_load_lds(
      (const __attribute__((address_space(1))) unsigned int*)g,
      (__attribute__((address_space(3))) unsigned int*)l, 16, 0, 0);
}
__device__ inline f32x4 mfma_bf16(short8 a, short8 b, f32x4 c) {
  return __builtin_amdgcn_mfma_f32_16x16x32_bf16(a, b, c, 0, 0, 0);
}

// ---------------------------------------------------------------------------
// Kernel 1: fp32 -> bf16 hi/lo split for x and W.  (unchanged)
// ---------------------------------------------------------------------------
__global__ __launch_bounds__(256) void cvt_hilo(const float* __restrict__ x,
                                                const float* __restrict__ W,
                                                unsigned short* __restrict__ xh,
                                                unsigned short* __restrict__ xl,
                                                unsigned short* __restrict__ wh,
                                                unsigned short* __restrict__ wl) {
  constexpr int NX4 = kM * kDin / 4;      // 4194304
  constexpr int NW4 = kDout * kDin / 4;   // 262144
  const int stride = gridDim.x * blockDim.x;
  for (int i = blockIdx.x * blockDim.x + threadIdx.x; i < NX4 + NW4; i += stride) {
    const bool isx = i < NX4;
    const int  j   = isx ? i : i - NX4;
    const float4 v = isx ? ((const float4*)x)[j] : ((const float4*)W)[j];
    const float e[4] = {v.x, v.y, v.z, v.w};
    us4 h, l;
#pragma unroll
    for (int q = 0; q < 4; ++q) {
      h[q] = f2bf(e[q]);
      l[q] = f2bf(e[q] - bf2f(h[q]));
    }
    if (isx) { ((us4*)xh)[j] = h; ((us4*)xl)[j] = l; }
    else     { ((us4*)wh)[j] = h; ((us4*)wl)[j] = l; }
  }
}

// ---------------------------------------------------------------------------
// Kernel 2: low[t][i][r] = x[i][:] . A[tuner[t]][r][:]  -> bf16  (unchanged)
// ---------------------------------------------------------------------------
__global__ __launch_bounds__(256) void lora_low(const float* __restrict__ x,
                                                const float* __restrict__ A,
                                                const int* __restrict__ tuner,
                                                unsigned short* __restrict__ lowb) {
  __shared__ float xs[64][34];  // [k][row]
  __shared__ float as[64][66];  // [k][t*16+r]
  const int tid = threadIdx.x;
  const int i0  = blockIdx.x * 32;
  const int tx  = tid & 15;   // col group (4 cols)
  const int ty  = tid >> 4;   // row group (2 rows)
  float acc[2][4] = {{0.f, 0.f, 0.f, 0.f}, {0.f, 0.f, 0.f, 0.f}};

  for (int kt = 0; kt < kDin; kt += 64) {
    __syncthreads();
#pragma unroll
    for (int p = 0; p < 2; ++p) {  // x tile: 32 rows x 64 k
      const int f = tid + p * 256;
      const int row = f >> 4, kq = (f & 15) * 4;
      const float4 v = *(const float4*)(x + (size_t)(i0 + row) * kDin + kt + kq);
      xs[kq + 0][row] = v.x; xs[kq + 1][row] = v.y;
      xs[kq + 2][row] = v.z; xs[kq + 3][row] = v.w;
    }
#pragma unroll
    for (int p = 0; p < 4; ++p) {  // A tile: 64 (t,r) rows x 64 k
      const int f = tid + p * 256;
      const int ar = f >> 4, kq = (f & 15) * 4;
      const int ti = tuner[ar >> 4];
      const float4 v = *(const float4*)(A + ((size_t)ti * kR + (ar & 15)) * kDin + kt + kq);
      as[kq + 0][ar] = v.x; as[kq + 1][ar] = v.y;
      as[kq + 2][ar] = v.z; as[kq + 3][ar] = v.w;
    }
    __syncthreads();
#pragma unroll 8
    for (int k = 0; k < 64; ++k) {
      const float a0 = xs[k][ty * 2], a1 = xs[k][ty * 2 + 1];
      const float b0 = as[k][tx * 4], b1 = as[k][tx * 4 + 1];
      const float b2 = as[k][tx * 4 + 2], b3 = as[k][tx * 4 + 3];
      acc[0][0] += a0 * b0; acc[0][1] += a0 * b1; acc[0][2] += a0 * b2; acc[0][3] += a0 * b3;
      acc[1][0] += a1 * b0; acc[1][1] += a1 * b1; acc[1][2] += a1 * b2; acc[1][3] += a1 * b3;
    }
  }
  // col c = tx*4+j  ->  t = tx>>2, r = (tx&3)*4+j
#pragma unroll
  for (int ii = 0; ii < 2; ++ii) {
    us4 o;
#pragma unroll
    for (int j = 0; j < 4; ++j) o[j] = f2bf(acc[ii][j]);
    *(us4*)(lowb + ((size_t)(tx >> 2) * kM + i0 + ty * 2 + ii) * kR + (tx & 3) * 4) = o;
  }
}

// ---------------------------------------------------------------------------
// Kernel 3: main MFMA GEMM (128x128 tile, BK=32) + per-t rank-16 MFMA epilogue.
// v4 changes vs round 5 (addressing only):
//  - XOR swizzle on the main-loop LDS tiles (both-sides-or-neither, rule #21):
//    chunk c (16B) of row r stored at position c ^ ((r>>1)&3).
//    * stage: linear LDS dest; per-lane global source chunk = (l&3)^((l>>3)&3)
//    * read:  csw = kg ^ ((rl>>1)&3) -> every 8-lane phase hits all 8
//      bank-quads (enumerated: g = {0,4,1,5,2,6,3,7})  -> conflict-free.
//  - counted-vmcnt double-buffer pipeline kept from round 5.
// ---------------------------------------------------------------------------
__global__ __launch_bounds__(256) void lora_main(
    const unsigned short* __restrict__ xh, const unsigned short* __restrict__ xl,
    const unsigned short* __restrict__ wh, const unsigned short* __restrict__ wl,
    const float* __restrict__ bias, const float* __restrict__ Bm,
    const int* __restrict__ tuner, const unsigned short* __restrict__ lowb,
    float* __restrict__ out) {
  __shared__ __align__(16) unsigned char smem[65536];
  const int tid  = threadIdx.x;
  const int lane = tid & 63;
  const int w    = tid >> 6;

  // XCD swizzle (1024 blocks, %8==0 -> simple form is bijective)
  const int swz = ((int)blockIdx.x & 7) * 128 + ((int)blockIdx.x >> 3);
  const int bm = swz >> 3, bn = swz & 7;
  const size_t i0 = (size_t)bm * 128, j0 = (size_t)bn * 128;
  const int wm = w >> 1, wn = w & 1;

  // staging source for this wave (wave w stages matrix w)
  const unsigned short* gsrc = (w == 0) ? xh : (w == 1) ? xl : (w == 2) ? wh : wl;
  const size_t grow0 = (w < 2) ? i0 : j0;
  // per-lane global offset: row = lane>>2, source chunk = (l&3)^((l>>3)&3)
  // (inverse-swizzled source; LDS dest stays linear for global_load_lds)
  const unsigned short* gbase =
      gsrc + (grow0 + (lane >> 2)) * kDin + ((lane & 3) ^ ((lane >> 3) & 3)) * 8;

  f32x4 acc[4][4];
#pragma unroll
  for (int m = 0; m < 4; ++m)
#pragma unroll
    for (int n = 0; n < 4; ++n) acc[m][n] = (f32x4){0.f, 0.f, 0.f, 0.f};

  const int kg = lane >> 4;   // k-group 0..3 (8 bf16 each)
  const int rl = lane & 15;
  // swizzled read: chunk kg of row (..+rl) lives at position kg^((rl>>1)&3)
  const int csw = kg ^ ((rl >> 1) & 3);
  const int rdA = (wm * 64 + rl) * 64 + csw * 16;
  const int rdB = (wn * 64 + rl) * 64 + csw * 16;

  auto compute_step = [&](const unsigned char* B0) {
    short8 ah[4], al[4], bh[4], bl[4];
#pragma unroll
    for (int m = 0; m < 4; ++m) {
      ah[m] = *(const short8*)(B0 +         rdA + m * 1024);
      al[m] = *(const short8*)(B0 +  8192 + rdA + m * 1024);
      bh[m] = *(const short8*)(B0 + 16384 + rdB + m * 1024);
      bl[m] = *(const short8*)(B0 + 24576 + rdB + m * 1024);
    }
    __builtin_amdgcn_s_setprio(1);
#pragma unroll
    for (int m = 0; m < 4; ++m)
#pragma unroll
      for (int n = 0; n < 4; ++n) {
        acc[m][n] = mfma_bf16(ah[m], bh[n], acc[m][n]);
        acc[m][n] = mfma_bf16(ah[m], bl[n], acc[m][n]);
        acc[m][n] = mfma_bf16(al[m], bh[n], acc[m][n]);
      }
    __builtin_amdgcn_s_setprio(0);
  };

  // prologue: stage K-step 0 into buf0 (8 loads in flight)
  {
    unsigned char* dst = smem + w * 8192;
#pragma unroll
    for (int c = 0; c < 8; ++c)
      gload_lds16(gbase + c * 16 * kDin, dst + c * 1024);
  }

  for (int s = 0; s < 31; ++s) {
    const int p = s & 1;
    {  // prefetch step s+1 into buf p^1 (16 loads now outstanding)
      unsigned char* dst = smem + (p ^ 1) * 32768 + w * 8192;
      const unsigned short* src = gbase + (s + 1) * 32;
#pragma unroll
      for (int c = 0; c < 8; ++c)
        gload_lds16(src + c * 16 * kDin, dst + c * 1024);
    }
    asm volatile("s_waitcnt vmcnt(8)" ::: "memory");  // step-s loads landed
    __builtin_amdgcn_s_barrier();
    asm volatile("" ::: "memory");
    compute_step(smem + p * 32768);
    asm volatile("s_waitcnt lgkmcnt(0)" ::: "memory");  // ds_reads of buf p retired
    __builtin_amdgcn_s_barrier();                       // buf p reusable next iter
    asm volatile("" ::: "memory");
  }
  // peeled last step (s=31, buf1): only its own 8 loads outstanding
  asm volatile("s_waitcnt vmcnt(0)" ::: "memory");
  __builtin_amdgcn_s_barrier();
  asm volatile("" ::: "memory");
  compute_step(smem + 32768);

  // pre-add bias into acc (col depends only on lane)
  float bv[4];
#pragma unroll
  for (int n = 0; n < 4; ++n) bv[n] = bias[j0 + wn * 64 + n * 16 + rl];
#pragma unroll
  for (int m = 0; m < 4; ++m)
#pragma unroll
    for (int n = 0; n < 4; ++n)
#pragma unroll
      for (int r = 0; r < 4; ++r) acc[m][n][r] += bv[n];

  // Epilogue tiles live in buf0's region, fragment-major [kg(4)][row(128)][16B]:
  // Lt at [0,8192) (kg2-3 = zero pad), Mt at [8192,16384).
  // (unswizzled; reads there are conflict-free by construction, ~free cost)
  {
    unsigned char* p = (tid < 128) ? (smem + 4096 + tid * 32)
                                   : (smem + 12288 + (tid - 128) * 32);
    const us8 z = {0, 0, 0, 0, 0, 0, 0, 0};
    *(us8*)p = z;
    *(us8*)(p + 16) = z;
  }

  for (int t = 0; t < kT; ++t) {
    __syncthreads();  // zeros visible / previous t's reads done
    {
      const int row = tid >> 1, half = tid & 1;
      // Lt (low tile, bf16)
      const us8 lv = *(const us8*)(lowb + ((size_t)t * kM + i0 + row) * kR + half * 8);
      *(us8*)(smem + half * 2048 + row * 16) = lv;
      // Mt (Bm tile, fp32 -> bf16)
      const int ti = tuner[t];
      const float* bp = Bm + ((size_t)ti * kDout + j0 + row) * kR + half * 8;
      const float4 m0 = *(const float4*)bp;
      const float4 m1 = *(const float4*)(bp + 4);
      us8 mv;
      mv[0] = f2bf(m0.x); mv[1] = f2bf(m0.y); mv[2] = f2bf(m0.z); mv[3] = f2bf(m0.w);
      mv[4] = f2bf(m1.x); mv[5] = f2bf(m1.y); mv[6] = f2bf(m1.z); mv[7] = f2bf(m1.w);
      *(us8*)(smem + 8192 + half * 2048 + row * 16) = mv;
    }
    __syncthreads();

    short8 lf[4], mf[4];
#pragma unroll
    for (int m = 0; m < 4; ++m)
      lf[m] = *(const short8*)(smem + kg * 2048 + (wm * 64 + m * 16 + rl) * 16);
#pragma unroll
    for (int n = 0; n < 4; ++n)
      mf[n] = *(const short8*)(smem + 8192 + kg * 2048 + (wn * 64 + n * 16 + rl) * 16);

#pragma unroll
    for (int m = 0; m < 4; ++m)
#pragma unroll
      for (int n = 0; n < 4; ++n) {
        const f32x4 d = mfma_bf16(lf[m], mf[n], acc[m][n]);
        const int r4  = wm * 64 + m * 16 + kg * 4;
        const int col = (int)j0 + wn * 64 + n * 16 + rl;
        const size_t base = ((size_t)t * kM + i0 + r4) * kDout + col;
        out[base]             = d[0];
        out[base + kDout]     = d[1];
        out[base + 2 * kDout] = d[2];
        out[base + 3 * kDout] = d[3];
      }
  }
}

// ---------------------------------------------------------------------------
extern "C" void kernel_launch(void* const* d_in, const int* in_sizes, int n_in,
                              void* d_out, int out_size, void* d_ws, size_t ws_size,
                              hipStream_t stream) {
  const float* x    = (const float*)d_in[0];
  const float* W    = (const float*)d_in[1];
  const float* bias = (const float*)d_in[2];
  const float* lA   = (const float*)d_in[3];
  const float* lB   = (const float*)d_in[4];
  const int*   ti   = (const int*)d_in[5];
  float* out = (float*)d_out;

  unsigned char* ws = (unsigned char*)d_ws;
  unsigned short* xh   = (unsigned short*)(ws + OFF_XH);
  unsigned short* xl   = (unsigned short*)(ws + OFF_XL);
  unsigned short* wh   = (unsigned short*)(ws + OFF_WH);
  unsigned short* wl   = (unsigned short*)(ws + OFF_WL);
  unsigned short* lowb = (unsigned short*)(ws + OFF_LOW);

  cvt_hilo<<<1024, 256, 0, stream>>>(x, W, xh, xl, wh, wl);
  lora_low<<<kM / 32, 256, 0, stream>>>(x, lA, ti, lowb);
  lora_main<<<1024, 256, 0, stream>>>(xh, xl, wh, wl, bias, lB, ti, lowb, out);
}

// Round 7
// 168.234 us; speedup vs baseline: 1.3598x; 1.3598x over previous
//
#include <hip/hip_runtime.h>

// out[t][i][j] = sum_k x[i][k]*W[j][k] + bias[j] + sum_r low[t][i][r]*Bm[ti][j][r]
// low[t][i][r] = sum_k x[i][k]*A[ti][r][k]
// Base GEMM in SINGLE-stream fp16 MFMA (10-bit mantissa; error ~1e-4 rms,
// ~100x below the 0.0156 reference slack). fp32 accumulate.

typedef __attribute__((ext_vector_type(8))) _Float16 f16x8;
typedef __attribute__((ext_vector_type(4))) float f32x4;
typedef __attribute__((ext_vector_type(4))) unsigned short us4;
typedef __attribute__((ext_vector_type(8))) unsigned short us8;

namespace {
constexpr int kM = 16384, kDin = 1024, kDout = 1024, kR = 16, kT = 4;
// d_ws byte offsets
constexpr size_t OFF_XF  = 0;               // [16384][1024] fp16 = 32 MiB
constexpr size_t OFF_WF  = 33554432;        // [1024][1024] fp16 = 2 MiB
constexpr size_t OFF_LOW = 35651584;        // [4][16384][16] fp16 = 2 MiB
}

__device__ inline unsigned short f2h(float f) {
  _Float16 h = (_Float16)f;  // RNE
  return __builtin_bit_cast(unsigned short, h);
}
__device__ inline void gload_lds16(const void* g, void* l) {
  __builtin_amdgcn_global_load_lds(
      (const __attribute__((address_space(1))) unsigned int*)g,
      (__attribute__((address_space(3))) unsigned int*)l, 16, 0, 0);
}
__device__ inline f32x4 mfma_f16(f16x8 a, f16x8 b, f32x4 c) {
  return __builtin_amdgcn_mfma_f32_16x16x32_f16(a, b, c, 0, 0, 0);
}

// ---------------------------------------------------------------------------
// Kernel 1: fp32 -> fp16 for x and W.
// ---------------------------------------------------------------------------
__global__ __launch_bounds__(256) void cvt_f16(const float* __restrict__ x,
                                               const float* __restrict__ W,
                                               unsigned short* __restrict__ xf,
                                               unsigned short* __restrict__ wf) {
  constexpr int NX4 = kM * kDin / 4;      // 4194304
  constexpr int NW4 = kDout * kDin / 4;   // 262144
  const int stride = gridDim.x * blockDim.x;
  for (int i = blockIdx.x * blockDim.x + threadIdx.x; i < NX4 + NW4; i += stride) {
    const bool isx = i < NX4;
    const int  j   = isx ? i : i - NX4;
    const float4 v = isx ? ((const float4*)x)[j] : ((const float4*)W)[j];
    us4 h;
    h[0] = f2h(v.x); h[1] = f2h(v.y); h[2] = f2h(v.z); h[3] = f2h(v.w);
    if (isx) ((us4*)xf)[j] = h;
    else     ((us4*)wf)[j] = h;
  }
}

// ---------------------------------------------------------------------------
// Kernel 2: low[t][i][r] = x[i][:] . A[tuner[t]][r][:]  -> fp16
// ---------------------------------------------------------------------------
__global__ __launch_bounds__(256) void lora_low(const float* __restrict__ x,
                                                const float* __restrict__ A,
                                                const int* __restrict__ tuner,
                                                unsigned short* __restrict__ lowb) {
  __shared__ float xs[64][34];  // [k][row]
  __shared__ float as[64][66];  // [k][t*16+r]
  const int tid = threadIdx.x;
  const int i0  = blockIdx.x * 32;
  const int tx  = tid & 15;   // col group (4 cols)
  const int ty  = tid >> 4;   // row group (2 rows)
  float acc[2][4] = {{0.f, 0.f, 0.f, 0.f}, {0.f, 0.f, 0.f, 0.f}};

  for (int kt = 0; kt < kDin; kt += 64) {
    __syncthreads();
#pragma unroll
    for (int p = 0; p < 2; ++p) {  // x tile: 32 rows x 64 k
      const int f = tid + p * 256;
      const int row = f >> 4, kq = (f & 15) * 4;
      const float4 v = *(const float4*)(x + (size_t)(i0 + row) * kDin + kt + kq);
      xs[kq + 0][row] = v.x; xs[kq + 1][row] = v.y;
      xs[kq + 2][row] = v.z; xs[kq + 3][row] = v.w;
    }
#pragma unroll
    for (int p = 0; p < 4; ++p) {  // A tile: 64 (t,r) rows x 64 k
      const int f = tid + p * 256;
      const int ar = f >> 4, kq = (f & 15) * 4;
      const int ti = tuner[ar >> 4];
      const float4 v = *(const float4*)(A + ((size_t)ti * kR + (ar & 15)) * kDin + kt + kq);
      as[kq + 0][ar] = v.x; as[kq + 1][ar] = v.y;
      as[kq + 2][ar] = v.z; as[kq + 3][ar] = v.w;
    }
    __syncthreads();
#pragma unroll 8
    for (int k = 0; k < 64; ++k) {
      const float a0 = xs[k][ty * 2], a1 = xs[k][ty * 2 + 1];
      const float b0 = as[k][tx * 4], b1 = as[k][tx * 4 + 1];
      const float b2 = as[k][tx * 4 + 2], b3 = as[k][tx * 4 + 3];
      acc[0][0] += a0 * b0; acc[0][1] += a0 * b1; acc[0][2] += a0 * b2; acc[0][3] += a0 * b3;
      acc[1][0] += a1 * b0; acc[1][1] += a1 * b1; acc[1][2] += a1 * b2; acc[1][3] += a1 * b3;
    }
  }
  // col c = tx*4+j  ->  t = tx>>2, r = (tx&3)*4+j
#pragma unroll
  for (int ii = 0; ii < 2; ++ii) {
    us4 o;
#pragma unroll
    for (int j = 0; j < 4; ++j) o[j] = f2h(acc[ii][j]);
    *(us4*)(lowb + ((size_t)(tx >> 2) * kM + i0 + ty * 2 + ii) * kR + (tx & 3) * 4) = o;
  }
}

// ---------------------------------------------------------------------------
// Kernel 3: main fp16 MFMA GEMM (128x128, BK=32) + per-t rank-16 epilogue.
// Single stream pair (xf, wf): LDS buffer 16 KB (A 8K + B 8K), double-buffered
// = 32 KB total -> 4-5 blocks/CU. Skeleton (XOR swizzle both-sides, counted
// vmcnt double-buffer pipeline, epilogue) carried from the passing kernel.
// Staging: waves 0,1 -> A halves; waves 2,3 -> B halves (4 gload_lds each).
// ---------------------------------------------------------------------------
__global__ __launch_bounds__(256) void lora_main(
    const unsigned short* __restrict__ xf, const unsigned short* __restrict__ wf,
    const float* __restrict__ bias, const float* __restrict__ Bm,
    const int* __restrict__ tuner, const unsigned short* __restrict__ lowb,
    float* __restrict__ out) {
  __shared__ __align__(16) unsigned char smem[32768];
  const int tid  = threadIdx.x;
  const int lane = tid & 63;
  const int w    = tid >> 6;

  // XCD swizzle (1024 blocks, %8==0 -> simple form is bijective)
  const int swz = ((int)blockIdx.x & 7) * 128 + ((int)blockIdx.x >> 3);
  const int bm = swz >> 3, bn = swz & 7;
  const size_t i0 = (size_t)bm * 128, j0 = (size_t)bn * 128;
  const int wm = w >> 1, wn = w & 1;

  // staging: waves 0,1 stage xf rows i0+{0..63},{64..127}; waves 2,3 stage wf.
  const int wp = w & 1;
  const unsigned short* gsrc = (w < 2) ? xf : wf;
  const size_t grow0 = ((w < 2) ? i0 : j0) + wp * 64;
  // per-lane source: row = grow0 + (lane>>2) (+16 per instr), chunk swizzled
  const unsigned short* gbase =
      gsrc + (grow0 + (lane >> 2)) * kDin + ((lane & 3) ^ ((lane >> 3) & 3)) * 8;
  const int stoff = (w >> 1) * 8192 + wp * 4096;  // this wave's dest region

  f32x4 acc[4][4];
#pragma unroll
  for (int m = 0; m < 4; ++m)
#pragma unroll
    for (int n = 0; n < 4; ++n) acc[m][n] = (f32x4){0.f, 0.f, 0.f, 0.f};

  const int kg = lane >> 4;   // k-group 0..3 (8 fp16 each)
  const int rl = lane & 15;
  // swizzled read: chunk kg of row r lives at position kg^((r>>1)&3)
  const int csw = kg ^ ((rl >> 1) & 3);
  const int rdA = (wm * 64 + rl) * 64 + csw * 16;           // in A region [0,8K)
  const int rdB = 8192 + (wn * 64 + rl) * 64 + csw * 16;    // in B region [8K,16K)

  auto compute_step = [&](const unsigned char* B0) {
    f16x8 a[4], b[4];
#pragma unroll
    for (int m = 0; m < 4; ++m) {
      a[m] = *(const f16x8*)(B0 + rdA + m * 1024);
      b[m] = *(const f16x8*)(B0 + rdB + m * 1024);
    }
    __builtin_amdgcn_s_setprio(1);
#pragma unroll
    for (int m = 0; m < 4; ++m)
#pragma unroll
      for (int n = 0; n < 4; ++n)
        acc[m][n] = mfma_f16(a[m], b[n], acc[m][n]);
    __builtin_amdgcn_s_setprio(0);
  };

  // prologue: stage K-step 0 into buf0 (4 loads/wave in flight)
  {
    unsigned char* dst = smem + stoff;
#pragma unroll
    for (int c = 0; c < 4; ++c)
      gload_lds16(gbase + c * 16 * kDin, dst + c * 1024);
  }

  for (int s = 0; s < 31; ++s) {
    const int p = s & 1;
    {  // prefetch step s+1 into buf p^1 (8 loads/wave now outstanding)
      unsigned char* dst = smem + (p ^ 1) * 16384 + stoff;
      const unsigned short* src = gbase + (s + 1) * 32;
#pragma unroll
      for (int c = 0; c < 4; ++c)
        gload_lds16(src + c * 16 * kDin, dst + c * 1024);
    }
    asm volatile("s_waitcnt vmcnt(4)" ::: "memory");  // step-s loads landed
    __builtin_amdgcn_s_barrier();
    asm volatile("" ::: "memory");
    compute_step(smem + p * 16384);
    asm volatile("s_waitcnt lgkmcnt(0)" ::: "memory");  // buf-p reads retired
    __builtin_amdgcn_s_barrier();                       // buf p reusable
    asm volatile("" ::: "memory");
  }
  // peeled last step (s=31, buf1): only its own 4 loads outstanding
  asm volatile("s_waitcnt vmcnt(0)" ::: "memory");
  __builtin_amdgcn_s_barrier();
  asm volatile("" ::: "memory");
  compute_step(smem + 16384);

  // pre-add bias into acc (col depends only on lane)
  float bv[4];
#pragma unroll
  for (int n = 0; n < 4; ++n) bv[n] = bias[j0 + wn * 64 + n * 16 + rl];
#pragma unroll
  for (int m = 0; m < 4; ++m)
#pragma unroll
    for (int n = 0; n < 4; ++n)
#pragma unroll
      for (int r = 0; r < 4; ++r) acc[m][n][r] += bv[n];

  // Epilogue tiles in [0,16K) (buf0 region; last compute read buf1 — disjoint).
  // Fragment-major [kg(4)][row(128)][16B]: Lt at [0,8192), Mt at [8192,16384).
  // Zero the k=16..31 pads (kg 2-3 of each).
  {
    unsigned char* p = (tid < 128) ? (smem + 4096 + tid * 32)
                                   : (smem + 12288 + (tid - 128) * 32);
    const us8 z = {0, 0, 0, 0, 0, 0, 0, 0};
    *(us8*)p = z;
    *(us8*)(p + 16) = z;
  }

  for (int t = 0; t < kT; ++t) {
    __syncthreads();  // zeros visible / previous t's reads done
    {
      const int row = tid >> 1, half = tid & 1;
      // Lt (low tile, fp16)
      const us8 lv = *(const us8*)(lowb + ((size_t)t * kM + i0 + row) * kR + half * 8);
      *(us8*)(smem + half * 2048 + row * 16) = lv;
      // Mt (Bm tile, fp32 -> fp16)
      const int ti = tuner[t];
      const float* bp = Bm + ((size_t)ti * kDout + j0 + row) * kR + half * 8;
      const float4 m0 = *(const float4*)bp;
      const float4 m1 = *(const float4*)(bp + 4);
      us8 mv;
      mv[0] = f2h(m0.x); mv[1] = f2h(m0.y); mv[2] = f2h(m0.z); mv[3] = f2h(m0.w);
      mv[4] = f2h(m1.x); mv[5] = f2h(m1.y); mv[6] = f2h(m1.z); mv[7] = f2h(m1.w);
      *(us8*)(smem + 8192 + half * 2048 + row * 16) = mv;
    }
    __syncthreads();

    f16x8 lf[4], mf[4];
#pragma unroll
    for (int m = 0; m < 4; ++m)
      lf[m] = *(const f16x8*)(smem + kg * 2048 + (wm * 64 + m * 16 + rl) * 16);
#pragma unroll
    for (int n = 0; n < 4; ++n)
      mf[n] = *(const f16x8*)(smem + 8192 + kg * 2048 + (wn * 64 + n * 16 + rl) * 16);

#pragma unroll
    for (int m = 0; m < 4; ++m)
#pragma unroll
      for (int n = 0; n < 4; ++n) {
        const f32x4 d = mfma_f16(lf[m], mf[n], acc[m][n]);
        const int r4  = wm * 64 + m * 16 + kg * 4;
        const int col = (int)j0 + wn * 64 + n * 16 + rl;
        const size_t base = ((size_t)t * kM + i0 + r4) * kDout + col;
        out[base]             = d[0];
        out[base + kDout]     = d[1];
        out[base + 2 * kDout] = d[2];
        out[base + 3 * kDout] = d[3];
      }
  }
}

// ---------------------------------------------------------------------------
extern "C" void kernel_launch(void* const* d_in, const int* in_sizes, int n_in,
                              void* d_out, int out_size, void* d_ws, size_t ws_size,
                              hipStream_t stream) {
  const float* x    = (const float*)d_in[0];
  const float* W    = (const float*)d_in[1];
  const float* bias = (const float*)d_in[2];
  const float* lA   = (const float*)d_in[3];
  const float* lB   = (const float*)d_in[4];
  const int*   ti   = (const int*)d_in[5];
  float* out = (float*)d_out;

  unsigned char* ws = (unsigned char*)d_ws;
  unsigned short* xfp  = (unsigned short*)(ws + OFF_XF);
  unsigned short* wfp  = (unsigned short*)(ws + OFF_WF);
  unsigned short* lowb = (unsigned short*)(ws + OFF_LOW);

  cvt_f16<<<1024, 256, 0, stream>>>(x, W, xfp, wfp);
  lora_low<<<kM / 32, 256, 0, stream>>>(x, lA, ti, lowb);
  lora_main<<<1024, 256, 0, stream>>>(xfp, wfp, bias, lB, ti, lowb, out);
}